// Round 10
// baseline (2084.098 us; speedup 1.0000x reference)
//
#include <hip/hip_runtime.h>
#include <cstdint>
#include <cstddef>

#define BN 64
#define TN 512
#define DN 256
#define UN 256
#define NC 768            // 3*UN, order: r | z | h
#define SLOTS (TN + 5)    // slots TN..TN+3 = initial states, TN+4 = zero slot
#define ZSLOT (TN + 4)
#define WL 6              // Ur/Uz rows per 32-row slice resident in LDS (96 KB total)

__device__ __forceinline__ float sigm(float x) {
  return 1.0f / (1.0f + __expf(-x));
}
__device__ __forceinline__ float tanh_fast(float x) {
  float e = __expf(-2.0f * x);
  return 2.0f / (1.0f + e) - 1.0f;
}

// ---------------- kernel 0: concat weights + biases ----------------
__global__ __launch_bounds__(256) void build_wcat(
    const float* __restrict__ Wr, const float* __restrict__ Wz, const float* __restrict__ Wh,
    const float* __restrict__ br, const float* __restrict__ bz, const float* __restrict__ bh,
    float* __restrict__ wcat, float* __restrict__ bias)
{
  int idx = blockIdx.x * 256 + threadIdx.x;
  if (idx < DN * NC) {
    int k = idx / NC, c = idx % NC;
    float v;
    if (c < 256)      v = Wr[k * UN + c];
    else if (c < 512) v = Wz[k * UN + (c - 256)];
    else              v = Wh[k * UN + (c - 512)];
    wcat[idx] = v;
  }
  if (idx < NC) {
    bias[idx] = (idx < 256) ? br[idx] : ((idx < 512) ? bz[idx - 256] : bh[idx - 512]);
  }
}

// ---------------- kernel 1: P = X @ Wcat + bias  (fp32, LDS-tiled) ----------------
__global__ __launch_bounds__(256) void gemm_xw(
    const float* __restrict__ X, const float* __restrict__ Wc,
    const float* __restrict__ bias, float* __restrict__ P)
{
  __shared__ float As[32][68];
  __shared__ float Bs[32][64];
  const int tid = threadIdx.x;
  const int m0 = blockIdx.x * 64;
  const int n0 = blockIdx.y * 64;
  const int ty = tid >> 4, tx = tid & 15;
  float acc[4][4] = {};

  const int ar = tid >> 3;
  const int ak = (tid & 7) * 4;
  const int bk = tid >> 4;
  const int bn = (tid & 15) * 4;

  for (int k0 = 0; k0 < DN; k0 += 32) {
    float4 a0 = *(const float4*)(X + (size_t)(m0 + ar) * DN + k0 + ak);
    float4 a1 = *(const float4*)(X + (size_t)(m0 + 32 + ar) * DN + k0 + ak);
    As[ak + 0][ar] = a0.x; As[ak + 1][ar] = a0.y; As[ak + 2][ar] = a0.z; As[ak + 3][ar] = a0.w;
    As[ak + 0][32 + ar] = a1.x; As[ak + 1][32 + ar] = a1.y; As[ak + 2][32 + ar] = a1.z; As[ak + 3][32 + ar] = a1.w;
    *(float4*)&Bs[bk][bn]      = *(const float4*)(Wc + (size_t)(k0 + bk) * NC + n0 + bn);
    *(float4*)&Bs[bk + 16][bn] = *(const float4*)(Wc + (size_t)(k0 + bk + 16) * NC + n0 + bn);
    __syncthreads();
#pragma unroll
    for (int kk = 0; kk < 32; kk++) {
      float4 av = *(const float4*)&As[kk][ty * 4];
      float4 bv = *(const float4*)&Bs[kk][tx * 4];
      acc[0][0] += av.x * bv.x; acc[0][1] += av.x * bv.y; acc[0][2] += av.x * bv.z; acc[0][3] += av.x * bv.w;
      acc[1][0] += av.y * bv.x; acc[1][1] += av.y * bv.y; acc[1][2] += av.y * bv.z; acc[1][3] += av.y * bv.w;
      acc[2][0] += av.z * bv.x; acc[2][1] += av.z * bv.y; acc[2][2] += av.z * bv.z; acc[2][3] += av.z * bv.w;
      acc[3][0] += av.w * bv.x; acc[3][1] += av.w * bv.y; acc[3][2] += av.w * bv.z; acc[3][3] += av.w * bv.w;
    }
    __syncthreads();
  }
  float4 bb = *(const float4*)(bias + n0 + tx * 4);
#pragma unroll
  for (int i = 0; i < 4; i++) {
    float4 o;
    o.x = acc[i][0] + bb.x; o.y = acc[i][1] + bb.y;
    o.z = acc[i][2] + bb.z; o.w = acc[i][3] + bb.w;
    *(float4*)(P + (size_t)(m0 + ty * 4 + i) * NC + n0 + tx * 4) = o;
  }
}

// ---------------- kernel 2: the recurrence, one block per batch ----------------
// R9 structure with the gather moved off the critical path:
//  - phase D prefetches next active step's gather (buf_s/pr/pz at eff[dep]) into ls/lpr/lpz[1..3]
//    and next lx into lx[], all hidden under the 416 KB weight stream;
//  - slots equal to the current step (not yet committed at D) are patched in the gates phase
//    from scur/prcur/pzcur (LDS, same thread index) -- the same trick g==0 always used;
//  - phase A and the E barrier are deleted: 4 barriers per active step, no global loads
//    on the serial chain. Arithmetic identical to R9 (same values, same order).
__global__ __launch_bounds__(1024, 4) void recurrent_kernel(
    const float* __restrict__ P,
    const float* __restrict__ Ur, const float* __restrict__ Uz, const float* __restrict__ Uh,
    const int* __restrict__ dep, const int* __restrict__ mask,
    const float* __restrict__ init,
    float* __restrict__ out,
    float* __restrict__ buf_s, float* __restrict__ buf_pr, float* __restrict__ buf_pz)
{
  const int b = blockIdx.x;
  const int tid = threadIdx.x;
  const int g = tid >> 8;
  const int u = tid & 255;
  const int wv = tid >> 6;        // 0..15
  const int mat = wv & 1;         // 0 = Ur, 1 = Uz
  const int s   = wv >> 1;        // 0..7 : 32-row slice
  const int l   = tid & 63;

  // --- Uh in VGPRs: column u, k in [64g, 64g+64) --- (identical to R0/R8/R9)
  float wh[64];
  {
    const float* p2 = Uh + (size_t)(64 * g) * UN + u;
#pragma unroll
    for (int kk = 0; kk < 64; kk++) {
      wh[kk] = p2[(size_t)kk * UN];
    }
  }
  const float* Um = mat ? Uz : Ur;

  __shared__ float4 wlds[2][8][WL][64];   // 96 KB LDS-resident weight rows
  __shared__ float ls[4][256], lpr[4][256], lpz[4][256];
  __shared__ float lx[NC];
  __shared__ float rs[256], hs[256], zv[256], hv[256];
  __shared__ float red0[4][256];
  __shared__ float redd[2][8][256];       // 16 KB
  __shared__ float scur[256], prcur[256], pzcur[256];
  __shared__ int eff[TN], nxt[TN + 1];
  __shared__ int mloc[TN];
  __shared__ int deploc[TN * 3];

  // stage LDS-resident weight rows: rows 32s..32s+WL-1 of each slice, both matrices
  for (int i = tid; i < 2 * 8 * WL * 64; i += 1024) {
    int mm = i / (8 * WL * 64);
    int r2 = i % (8 * WL * 64);
    int ss = r2 / (WL * 64);
    int rr = (r2 / 64) % WL;
    int ll = i & 63;
    wlds[mm][ss][rr][ll] = ((const float4*)(mm ? Uz : Ur))[(size_t)(32 * ss + rr) * 64 + ll];
  }
  for (int i = tid; i < TN; i += 1024) mloc[i] = mask[b * TN + i];
  for (int i = tid; i < TN * 3; i += 1024) deploc[i] = dep[i];

  const size_t bufBase = (size_t)b * SLOTS * UN;

  // prologue: stage initial states, zero slot, current-state LDS  (identical to R9)
  {
    float v = init[((size_t)g * BN + b) * UN + u];
    ls[g][u] = v;
    buf_s[bufBase + (size_t)(TN + g) * UN + u] = v;
    if (tid < 256) {
      scur[u] = 0.0f; prcur[u] = 0.0f; pzcur[u] = 0.0f;
      buf_s[bufBase + (size_t)ZSLOT * UN + u] = 0.0f;
      buf_pr[bufBase + (size_t)ZSLOT * UN + u] = 0.0f;
      buf_pz[bufBase + (size_t)ZSLOT * UN + u] = 0.0f;
    }
  }
  __syncthreads();

  // eff[] (last active <= t, else ZSLOT) and nxt[] (next active >= t, else TN)
  if (tid == 0) {
    int e = ZSLOT;
    for (int t2 = 0; t2 < TN; t2++) { if (mloc[t2]) e = t2; eff[t2] = e; }
  } else if (tid == 64) {
    nxt[TN] = TN;
    int e = TN;
    for (int t2 = TN - 1; t2 >= 0; t2--) { if (mloc[t2]) e = t2; nxt[t2] = e; }
  }

  // ---- D-phase projection of a 256-vector through Ur|Uz: WL LDS rows + streamed rows ----
  auto projD = [&](const float* hsrc) {
    const float* hb = hsrc + 32 * s;
    float4 a = {0, 0, 0, 0};
#pragma unroll
    for (int r = 0; r < WL; r++) {
      float hk = hb[r];
      float4 w = wlds[mat][s][r][l];
      a.x = fmaf(hk, w.x, a.x); a.y = fmaf(hk, w.y, a.y);
      a.z = fmaf(hk, w.z, a.z); a.w = fmaf(hk, w.w, a.w);
    }
    const float4* p = (const float4*)Um + (size_t)(32 * s + WL) * 64 + l;
#pragma unroll 4
    for (int r = 0; r < 32 - WL; r++) {
      float hk = hb[WL + r];
      float4 w = p[(size_t)r * 64];
      a.x = fmaf(hk, w.x, a.x); a.y = fmaf(hk, w.y, a.y);
      a.z = fmaf(hk, w.z, a.z); a.w = fmaf(hk, w.w, a.w);
    }
    *(float4*)&redd[mat][s][4 * l] = a;
  };

  // initial-state projections through Ur and Uz (identical to R9)
#pragma unroll 1
  for (int gg = 0; gg < 4; gg++) {
    projD(&ls[gg][0]);
    __syncthreads();
    if (tid < 256) {
      float prn = 0.0f, pzn = 0.0f;
#pragma unroll
      for (int q = 0; q < 8; q++) { prn += redd[0][q][tid]; pzn += redd[1][q][tid]; }
      buf_pr[bufBase + (size_t)(TN + gg) * UN + tid] = prn;
      buf_pz[bufBase + (size_t)(TN + gg) * UN + tid] = pzn;
    }
    __syncthreads();
  }

  const size_t outB = (size_t)b * TN * UN;
  const size_t pB = (size_t)b * TN * NC;

  // preload lx for the first active step
  {
    int t0 = nxt[0];
    if (t0 < TN && tid < NC) lx[tid] = P[pB + (size_t)t0 * NC + tid];
  }
  __syncthreads();

  bool havePre = false;   // gather for current step was prefetched in previous D
  int tprev = -1;         // previous active step index (block-uniform)

#pragma unroll 1
  for (int t = 0; t < TN; t++) {
    if (mloc[t] == 0) {
      if (tid < 256) out[outB + (size_t)t * UN + u] = 0.0f;
      continue;                    // no barrier, no LDS touch
    }
    // ---- gates (tid<256): sources from prefetch/patch (hot) or inline gather (cold) ----
    if (tid < 256) {
      float xr = lx[u], xz = lx[256 + u];
      float s0, p0, q0, s1, p1, q1, s2, p2, q2, s3, p3, q3;
      if (havePre) {
        s0 = scur[u]; p0 = prcur[u]; q0 = pzcur[u];
        int d1 = eff[deploc[(t - 1) * 3 + 0]];
        int d2 = eff[deploc[(t - 1) * 3 + 1]];
        int d3 = eff[deploc[(t - 1) * 3 + 2]];
        s1 = (d1 == tprev) ? scur[u] : ls[1][u];
        p1 = (d1 == tprev) ? prcur[u] : lpr[1][u];
        q1 = (d1 == tprev) ? pzcur[u] : lpz[1][u];
        s2 = (d2 == tprev) ? scur[u] : ls[2][u];
        p2 = (d2 == tprev) ? prcur[u] : lpr[2][u];
        q2 = (d2 == tprev) ? pzcur[u] : lpz[2][u];
        s3 = (d3 == tprev) ? scur[u] : ls[3][u];
        p3 = (d3 == tprev) ? prcur[u] : lpr[3][u];
        q3 = (d3 == tprev) ? pzcur[u] : lpz[3][u];
      } else if (t == 0) {
        size_t b0 = bufBase + (size_t)(TN + 0) * UN + u;
        size_t b1 = bufBase + (size_t)(TN + 1) * UN + u;
        size_t b2 = bufBase + (size_t)(TN + 2) * UN + u;
        size_t b3 = bufBase + (size_t)(TN + 3) * UN + u;
        s0 = buf_s[b0]; p0 = buf_pr[b0]; q0 = buf_pz[b0];
        s1 = buf_s[b1]; p1 = buf_pr[b1]; q1 = buf_pz[b1];
        s2 = buf_s[b2]; p2 = buf_pr[b2]; q2 = buf_pz[b2];
        s3 = buf_s[b3]; p3 = buf_pr[b3]; q3 = buf_pz[b3];
      } else {
        // cold, t>0 (first active step): no prior commits, eff[*] is ZSLOT
        s0 = scur[u]; p0 = prcur[u]; q0 = pzcur[u];
        size_t b1 = bufBase + (size_t)eff[deploc[(t - 1) * 3 + 0]] * UN + u;
        size_t b2 = bufBase + (size_t)eff[deploc[(t - 1) * 3 + 1]] * UN + u;
        size_t b3 = bufBase + (size_t)eff[deploc[(t - 1) * 3 + 2]] * UN + u;
        s1 = buf_s[b1]; p1 = buf_pr[b1]; q1 = buf_pz[b1];
        s2 = buf_s[b2]; p2 = buf_pr[b2]; q2 = buf_pz[b2];
        s3 = buf_s[b3]; p3 = buf_pr[b3]; q3 = buf_pz[b3];
      }
      float r0 = sigm(xr + p0);
      float r1 = sigm(xr + p1);
      float r2 = sigm(xr + p2);
      float r3 = sigm(xr + p3);
      rs[u] = r0 * s0 + r1 * s1 + r2 * s2 + r3 * s3;
      hs[u] = (s0 + s1) + (s2 + s3);
      zv[u] = sigm(xz + ((q0 + q1) + (q2 + q3)));
    }
    __syncthreads();                               // bar1: rs/hs/zv ready
    // ---- B: live matvec rs @ Uh (register-resident Uh) ---- (identical to R9)
    {
      float a0 = 0, a1 = 0, a2 = 0, a3 = 0;
      const float4* v4 = (const float4*)&rs[64 * g];
#pragma unroll
      for (int kk = 0; kk < 16; kk++) {
        float4 v = v4[kk];
        a0 += v.x * wh[4 * kk];     a1 += v.y * wh[4 * kk + 1];
        a2 += v.z * wh[4 * kk + 2]; a3 += v.w * wh[4 * kk + 3];
      }
      red0[g][u] = (a0 + a1) + (a2 + a3);
    }
    __syncthreads();                               // bar2: red0 ready
    // ---- C: h, output ---- (identical to R9)
    if (tid < 256) {
      float ht = tanh_fast(lx[512 + u] + ((red0[0][u] + red0[1][u]) + (red0[2][u] + red0[3][u])));
      float z = zv[u];
      float h = z * hs[u] * 0.25f + (1.0f - z) * ht;
      hv[u] = h; scur[u] = h;
      out[outB + (size_t)t * UN + u] = h;
    }
    __syncthreads();                               // bar3: hv/scur ready
    // ---- D: prefetch next step's gather + lx (hidden under weight stream) + projections ----
    {
      const int tn = nxt[t + 1];                   // block-uniform
      if (tn < TN) {
        if (tid < NC) lx[tid] = P[pB + (size_t)tn * NC + tid];
        if (tid < 768) {
          int gi = tid >> 8;                       // 0..2
          int srcp = eff[deploc[(tn - 1) * 3 + gi]];
          if (srcp != t) {                         // slot t commits in E; patched at gates
            size_t base = bufBase + (size_t)srcp * UN + u;
            ls[gi + 1][u]  = buf_s[base];
            lpr[gi + 1][u] = buf_pr[base];
            lpz[gi + 1][u] = buf_pz[base];
          }
        }
      }
    }
    projD(hv);
    __syncthreads();                               // bar4: redd + prefetches ready
    // ---- E: commit state + cached projections (no trailing barrier needed) ----
    if (tid < 256) {
      float prn = 0.0f, pzn = 0.0f;
#pragma unroll
      for (int q = 0; q < 8; q++) { prn += redd[0][q][tid]; pzn += redd[1][q][tid]; }
      prcur[tid] = prn; pzcur[tid] = pzn;
      size_t base = bufBase + (size_t)t * UN + tid;
      buf_s[base]  = hv[tid];
      buf_pr[base] = prn;
      buf_pz[base] = pzn;
    }
    tprev = t;
    havePre = true;
  }

  // epilogue: last_out, last_state (identical to R9)
  if (tid < 256) {
    float lst = scur[u];
    out[(size_t)BN * TN * UN + (size_t)b * UN + u] = mloc[TN - 1] ? lst : 0.0f;
    out[(size_t)BN * TN * UN + (size_t)BN * UN + (size_t)b * UN + u] = lst;
  }
}

extern "C" void kernel_launch(void* const* d_in, const int* in_sizes, int n_in,
                              void* d_out, int out_size, void* d_ws, size_t ws_size,
                              hipStream_t stream) {
  const float* inputs       = (const float*)d_in[0];
  const int*   dependencies = (const int*)d_in[1];
  const int*   mask         = (const int*)d_in[2];
  const float* initial      = (const float*)d_in[3];
  const float* Wz = (const float*)d_in[4];
  const float* Wr = (const float*)d_in[5];
  const float* Wh = (const float*)d_in[6];
  const float* Uz = (const float*)d_in[7];
  const float* Ur = (const float*)d_in[8];
  const float* Uh = (const float*)d_in[9];
  const float* bz = (const float*)d_in[10];
  const float* br = (const float*)d_in[11];
  const float* bh = (const float*)d_in[12];

  float* out = (float*)d_out;
  float* ws  = (float*)d_ws;
  float* wcat    = ws;                                   // 256*768
  float* bias    = wcat + (size_t)DN * NC;               // 768
  float* precomp = bias + NC;                            // B*T*768
  float* buf_s   = precomp + (size_t)BN * TN * NC;       // B*SLOTS*256 each
  float* buf_pr  = buf_s + (size_t)BN * SLOTS * UN;
  float* buf_pz  = buf_pr + (size_t)BN * SLOTS * UN;

  build_wcat<<<(DN * NC + 255) / 256, 256, 0, stream>>>(Wr, Wz, Wh, br, bz, bh, wcat, bias);
  gemm_xw<<<dim3(BN * TN / 64, NC / 64), 256, 0, stream>>>(inputs, wcat, bias, precomp);
  recurrent_kernel<<<BN, 1024, 0, stream>>>(precomp, Ur, Uz, Uh, dependencies, mask, initial,
                                            out, buf_s, buf_pr, buf_pz);
}

// Round 11
// 1835.820 us; speedup vs baseline: 1.1352x; 1.1352x over previous
//
#include <hip/hip_runtime.h>
#include <cstdint>
#include <cstddef>

#define BN 64
#define TN 512
#define DN 256
#define UN 256
#define NC 768            // 3*UN, order: r | z | h
#define SLOTS (TN + 5)    // slots TN..TN+3 = initial states, TN+4 = zero slot
#define ZSLOT (TN + 4)
#define WL 6              // Ur/Uz rows per 32-row slice resident in LDS (96 KB total)

__device__ __forceinline__ float sigm(float x) {
  return 1.0f / (1.0f + __expf(-x));
}
__device__ __forceinline__ float tanh_fast(float x) {
  float e = __expf(-2.0f * x);
  return 2.0f / (1.0f + e) - 1.0f;
}

// ---------------- kernel 0: concat weights + biases ----------------
__global__ __launch_bounds__(256) void build_wcat(
    const float* __restrict__ Wr, const float* __restrict__ Wz, const float* __restrict__ Wh,
    const float* __restrict__ br, const float* __restrict__ bz, const float* __restrict__ bh,
    float* __restrict__ wcat, float* __restrict__ bias)
{
  int idx = blockIdx.x * 256 + threadIdx.x;
  if (idx < DN * NC) {
    int k = idx / NC, c = idx % NC;
    float v;
    if (c < 256)      v = Wr[k * UN + c];
    else if (c < 512) v = Wz[k * UN + (c - 256)];
    else              v = Wh[k * UN + (c - 512)];
    wcat[idx] = v;
  }
  if (idx < NC) {
    bias[idx] = (idx < 256) ? br[idx] : ((idx < 512) ? bz[idx - 256] : bh[idx - 512]);
  }
}

// ---------------- kernel 1: P = X @ Wcat + bias  (fp32, LDS-tiled) ----------------
__global__ __launch_bounds__(256) void gemm_xw(
    const float* __restrict__ X, const float* __restrict__ Wc,
    const float* __restrict__ bias, float* __restrict__ P)
{
  __shared__ float As[32][68];
  __shared__ float Bs[32][64];
  const int tid = threadIdx.x;
  const int m0 = blockIdx.x * 64;
  const int n0 = blockIdx.y * 64;
  const int ty = tid >> 4, tx = tid & 15;
  float acc[4][4] = {};

  const int ar = tid >> 3;
  const int ak = (tid & 7) * 4;
  const int bk = tid >> 4;
  const int bn = (tid & 15) * 4;

  for (int k0 = 0; k0 < DN; k0 += 32) {
    float4 a0 = *(const float4*)(X + (size_t)(m0 + ar) * DN + k0 + ak);
    float4 a1 = *(const float4*)(X + (size_t)(m0 + 32 + ar) * DN + k0 + ak);
    As[ak + 0][ar] = a0.x; As[ak + 1][ar] = a0.y; As[ak + 2][ar] = a0.z; As[ak + 3][ar] = a0.w;
    As[ak + 0][32 + ar] = a1.x; As[ak + 1][32 + ar] = a1.y; As[ak + 2][32 + ar] = a1.z; As[ak + 3][32 + ar] = a1.w;
    *(float4*)&Bs[bk][bn]      = *(const float4*)(Wc + (size_t)(k0 + bk) * NC + n0 + bn);
    *(float4*)&Bs[bk + 16][bn] = *(const float4*)(Wc + (size_t)(k0 + bk + 16) * NC + n0 + bn);
    __syncthreads();
#pragma unroll
    for (int kk = 0; kk < 32; kk++) {
      float4 av = *(const float4*)&As[kk][ty * 4];
      float4 bv = *(const float4*)&Bs[kk][tx * 4];
      acc[0][0] += av.x * bv.x; acc[0][1] += av.x * bv.y; acc[0][2] += av.x * bv.z; acc[0][3] += av.x * bv.w;
      acc[1][0] += av.y * bv.x; acc[1][1] += av.y * bv.y; acc[1][2] += av.y * bv.z; acc[1][3] += av.y * bv.w;
      acc[2][0] += av.z * bv.x; acc[2][1] += av.z * bv.y; acc[2][2] += av.z * bv.z; acc[2][3] += av.z * bv.w;
      acc[3][0] += av.w * bv.x; acc[3][1] += av.w * bv.y; acc[3][2] += av.w * bv.z; acc[3][3] += av.w * bv.w;
    }
    __syncthreads();
  }
  float4 bb = *(const float4*)(bias + n0 + tx * 4);
#pragma unroll
  for (int i = 0; i < 4; i++) {
    float4 o;
    o.x = acc[i][0] + bb.x; o.y = acc[i][1] + bb.y;
    o.z = acc[i][2] + bb.z; o.w = acc[i][3] + bb.w;
    *(float4*)(P + (size_t)(m0 + ty * 4 + i) * NC + n0 + tx * 4) = o;
  }
}

// ---------------- kernel 2: the recurrence, one block per batch ----------------
// R8 structure (1658 us) with two surgical latency edits (== R9, best measured: 1622 us):
//  (1) eff[]/nxt[] precomputed from mask; masked steps are barrier-free (out-zero + continue).
//  (2) next active step's x-row loaded global->LDS inside phase D (lx is dead there; the load
//      is the oldest outstanding VMEM op so D's barrier drain is free). A no longer loads lx.
// NOTE (measured, R10): do NOT move the buf_s/pr/pz gather into phase D — same bytes, different
// timing, thrashes L2 (+7.4 MB HBM write-back) and regresses 250 us. The A-phase gather in its
// own quiet window is load-bearing for cache residency.
__global__ __launch_bounds__(1024, 4) void recurrent_kernel(
    const float* __restrict__ P,
    const float* __restrict__ Ur, const float* __restrict__ Uz, const float* __restrict__ Uh,
    const int* __restrict__ dep, const int* __restrict__ mask,
    const float* __restrict__ init,
    float* __restrict__ out,
    float* __restrict__ buf_s, float* __restrict__ buf_pr, float* __restrict__ buf_pz)
{
  const int b = blockIdx.x;
  const int tid = threadIdx.x;
  const int g = tid >> 8;
  const int u = tid & 255;
  const int wv = tid >> 6;        // 0..15
  const int mat = wv & 1;         // 0 = Ur, 1 = Uz
  const int s   = wv >> 1;        // 0..7 : 32-row slice
  const int l   = tid & 63;

  // --- Uh in VGPRs: column u, k in [64g, 64g+64) ---
  float wh[64];
  {
    const float* p2 = Uh + (size_t)(64 * g) * UN + u;
#pragma unroll
    for (int kk = 0; kk < 64; kk++) {
      wh[kk] = p2[(size_t)kk * UN];
    }
  }
  const float* Um = mat ? Uz : Ur;

  __shared__ float4 wlds[2][8][WL][64];   // 96 KB LDS-resident weight rows
  __shared__ float ls[4][256], lpr[4][256], lpz[4][256];
  __shared__ float lx[NC];
  __shared__ float rs[256], hs[256], zv[256], hv[256];
  __shared__ float red0[4][256];
  __shared__ float redd[2][8][256];       // 16 KB
  __shared__ float scur[256], prcur[256], pzcur[256];
  __shared__ int eff[TN], nxt[TN + 1];
  __shared__ int mloc[TN];
  __shared__ int deploc[TN * 3];

  // stage LDS-resident weight rows: rows 32s..32s+WL-1 of each slice, both matrices
  for (int i = tid; i < 2 * 8 * WL * 64; i += 1024) {
    int mm = i / (8 * WL * 64);
    int r2 = i % (8 * WL * 64);
    int ss = r2 / (WL * 64);
    int rr = (r2 / 64) % WL;
    int ll = i & 63;
    wlds[mm][ss][rr][ll] = ((const float4*)(mm ? Uz : Ur))[(size_t)(32 * ss + rr) * 64 + ll];
  }
  for (int i = tid; i < TN; i += 1024) mloc[i] = mask[b * TN + i];
  for (int i = tid; i < TN * 3; i += 1024) deploc[i] = dep[i];

  const size_t bufBase = (size_t)b * SLOTS * UN;

  // prologue: stage initial states, zero slot, current-state LDS
  {
    float v = init[((size_t)g * BN + b) * UN + u];
    ls[g][u] = v;
    buf_s[bufBase + (size_t)(TN + g) * UN + u] = v;
    if (tid < 256) {
      scur[u] = 0.0f; prcur[u] = 0.0f; pzcur[u] = 0.0f;
      buf_s[bufBase + (size_t)ZSLOT * UN + u] = 0.0f;
      buf_pr[bufBase + (size_t)ZSLOT * UN + u] = 0.0f;
      buf_pz[bufBase + (size_t)ZSLOT * UN + u] = 0.0f;
    }
  }
  __syncthreads();

  // eff[] (last active <= t, else ZSLOT) and nxt[] (next active >= t, else TN):
  // pure functions of mask, computed once (visibility covered by prologue barriers)
  if (tid == 0) {
    int e = ZSLOT;
    for (int t2 = 0; t2 < TN; t2++) { if (mloc[t2]) e = t2; eff[t2] = e; }
  } else if (tid == 64) {
    nxt[TN] = TN;
    int e = TN;
    for (int t2 = TN - 1; t2 >= 0; t2--) { if (mloc[t2]) e = t2; nxt[t2] = e; }
  }

  // ---- D-phase projection of a 256-vector through Ur|Uz: WL LDS rows + streamed rows ----
  auto projD = [&](const float* hsrc) {
    const float* hb = hsrc + 32 * s;
    float4 a = {0, 0, 0, 0};
#pragma unroll
    for (int r = 0; r < WL; r++) {
      float hk = hb[r];
      float4 w = wlds[mat][s][r][l];
      a.x = fmaf(hk, w.x, a.x); a.y = fmaf(hk, w.y, a.y);
      a.z = fmaf(hk, w.z, a.z); a.w = fmaf(hk, w.w, a.w);
    }
    const float4* p = (const float4*)Um + (size_t)(32 * s + WL) * 64 + l;
#pragma unroll 4
    for (int r = 0; r < 32 - WL; r++) {
      float hk = hb[WL + r];
      float4 w = p[(size_t)r * 64];
      a.x = fmaf(hk, w.x, a.x); a.y = fmaf(hk, w.y, a.y);
      a.z = fmaf(hk, w.z, a.z); a.w = fmaf(hk, w.w, a.w);
    }
    *(float4*)&redd[mat][s][4 * l] = a;
  };

  // initial-state projections through Ur and Uz
#pragma unroll 1
  for (int gg = 0; gg < 4; gg++) {
    projD(&ls[gg][0]);
    __syncthreads();
    if (tid < 256) {
      float prn = 0.0f, pzn = 0.0f;
#pragma unroll
      for (int q = 0; q < 8; q++) { prn += redd[0][q][tid]; pzn += redd[1][q][tid]; }
      buf_pr[bufBase + (size_t)(TN + gg) * UN + tid] = prn;
      buf_pz[bufBase + (size_t)(TN + gg) * UN + tid] = pzn;
    }
    __syncthreads();
  }

  const size_t outB = (size_t)b * TN * UN;
  const size_t pB = (size_t)b * TN * NC;

  // preload lx for the first active step
  {
    int t0 = nxt[0];
    if (t0 < TN && tid < NC) lx[tid] = P[pB + (size_t)t0 * NC + tid];
  }
  __syncthreads();

#pragma unroll 1
  for (int t = 0; t < TN; t++) {
    if (mloc[t] == 0) {
      if (tid < 256) out[outB + (size_t)t * UN + u] = 0.0f;
      continue;                    // eff/nxt precomputed: no barrier, no LDS touch
    }
    // ---- A: gather 4 source states + cached projections ----
    if (t > 0 && g == 0) {
      ls[0][u] = scur[u]; lpr[0][u] = prcur[u]; lpz[0][u] = pzcur[u];
    } else {
      int src = (t == 0) ? (TN + g) : eff[deploc[(t - 1) * 3 + (g - 1)]];
      size_t base = bufBase + (size_t)src * UN + u;
      ls[g][u]  = buf_s[base];
      lpr[g][u] = buf_pr[base];
      lpz[g][u] = buf_pz[base];
    }
    __syncthreads();
    // ---- A': gates (elementwise) ----
    if (tid < 256) {
      float s0 = ls[0][u], s1 = ls[1][u], s2 = ls[2][u], s3 = ls[3][u];
      float xr = lx[u];
      float r0 = sigm(xr + lpr[0][u]);
      float r1 = sigm(xr + lpr[1][u]);
      float r2 = sigm(xr + lpr[2][u]);
      float r3 = sigm(xr + lpr[3][u]);
      rs[u] = r0 * s0 + r1 * s1 + r2 * s2 + r3 * s3;
      hs[u] = (s0 + s1) + (s2 + s3);
      zv[u] = sigm(lx[256 + u] + ((lpz[0][u] + lpz[1][u]) + (lpz[2][u] + lpz[3][u])));
    }
    __syncthreads();
    // ---- B: live matvec rs @ Uh (register-resident Uh) ----
    {
      float a0 = 0, a1 = 0, a2 = 0, a3 = 0;
      const float4* v4 = (const float4*)&rs[64 * g];
#pragma unroll
      for (int kk = 0; kk < 16; kk++) {
        float4 v = v4[kk];
        a0 += v.x * wh[4 * kk];     a1 += v.y * wh[4 * kk + 1];
        a2 += v.z * wh[4 * kk + 2]; a3 += v.w * wh[4 * kk + 3];
      }
      red0[g][u] = (a0 + a1) + (a2 + a3);
    }
    __syncthreads();
    // ---- C: h, output ---- (last reader of lx)
    if (tid < 256) {
      float ht = tanh_fast(lx[512 + u] + ((red0[0][u] + red0[1][u]) + (red0[2][u] + red0[3][u])));
      float z = zv[u];
      float h = z * hs[u] * 0.25f + (1.0f - z) * ht;
      hv[u] = h; scur[u] = h;
      out[outB + (size_t)t * UN + u] = h;
    }
    __syncthreads();
    // ---- D: next-lx refill (oldest VMEM op; hides under weight stream) + projections ----
    {
      const int tn = nxt[t + 1];                 // block-uniform
      if (tn < TN && tid < NC) lx[tid] = P[pB + (size_t)tn * NC + tid];
    }
    projD(hv);
    __syncthreads();
    // ---- E: commit state + cached projections ----
    if (tid < 256) {
      float prn = 0.0f, pzn = 0.0f;
#pragma unroll
      for (int q = 0; q < 8; q++) { prn += redd[0][q][tid]; pzn += redd[1][q][tid]; }
      prcur[tid] = prn; pzcur[tid] = pzn;
      size_t base = bufBase + (size_t)t * UN + tid;
      buf_s[base]  = hv[tid];
      buf_pr[base] = prn;
      buf_pz[base] = pzn;
    }
    __syncthreads();
  }

  // epilogue: last_out, last_state
  if (tid < 256) {
    float lst = scur[u];
    out[(size_t)BN * TN * UN + (size_t)b * UN + u] = mloc[TN - 1] ? lst : 0.0f;
    out[(size_t)BN * TN * UN + (size_t)BN * UN + (size_t)b * UN + u] = lst;
  }
}

extern "C" void kernel_launch(void* const* d_in, const int* in_sizes, int n_in,
                              void* d_out, int out_size, void* d_ws, size_t ws_size,
                              hipStream_t stream) {
  const float* inputs       = (const float*)d_in[0];
  const int*   dependencies = (const int*)d_in[1];
  const int*   mask         = (const int*)d_in[2];
  const float* initial      = (const float*)d_in[3];
  const float* Wz = (const float*)d_in[4];
  const float* Wr = (const float*)d_in[5];
  const float* Wh = (const float*)d_in[6];
  const float* Uz = (const float*)d_in[7];
  const float* Ur = (const float*)d_in[8];
  const float* Uh = (const float*)d_in[9];
  const float* bz = (const float*)d_in[10];
  const float* br = (const float*)d_in[11];
  const float* bh = (const float*)d_in[12];

  float* out = (float*)d_out;
  float* ws  = (float*)d_ws;
  float* wcat    = ws;                                   // 256*768
  float* bias    = wcat + (size_t)DN * NC;               // 768
  float* precomp = bias + NC;                            // B*T*768
  float* buf_s   = precomp + (size_t)BN * TN * NC;       // B*SLOTS*256 each
  float* buf_pr  = buf_s + (size_t)BN * SLOTS * UN;
  float* buf_pz  = buf_pr + (size_t)BN * SLOTS * UN;

  build_wcat<<<(DN * NC + 255) / 256, 256, 0, stream>>>(Wr, Wz, Wh, br, bz, bh, wcat, bias);
  gemm_xw<<<dim3(BN * TN / 64, NC / 64), 256, 0, stream>>>(inputs, wcat, bias, precomp);
  recurrent_kernel<<<BN, 1024, 0, stream>>>(precomp, Ur, Uz, Uh, dependencies, mask, initial,
                                            out, buf_s, buf_pr, buf_pz);
}